// Round 6
// baseline (73.406 us; speedup 1.0000x reference)
//
#include <hip/hip_runtime.h>
#include <hip/hip_bf16.h>
#include <stdint.h>

// FullTucker: Z = U0 @ einsum('pqr,qb,rb->pb', G, U1^T@X1, U2^T@X2)
// D_OUT=D1=D2=512, R0=R1=R2=128, BATCH=8192. f32 in/out; bf16 MFMA inside.
// k_core: core[p,b] = sum_q x1[q,b] * (sum_r G[p,q,r]*u2[r,b])
//   WAVE-AUTONOMOUS main loop: each wave has a private 2-deep LDS ring for its
//   own 32 G-rows, staged by its own global_load_lds and gated by its own
//   counted s_waitcnt vmcnt (vmcnt retires in issue order -> per-wave pipeline,
//   NO barriers). B (UX2T) hoisted 128 VGPR; x1 folded post-MFMA in f32.

typedef __attribute__((ext_vector_type(8))) short bf8;   // 8 bf16 (4 VGPR)
typedef __attribute__((ext_vector_type(4))) short bf4;   // 4 bf16 (8B)
typedef __attribute__((ext_vector_type(4))) float f4;    // 4 f32

__device__ __forceinline__ unsigned short f2bf(float f){
  unsigned x = __builtin_bit_cast(unsigned, f);
  x += 0x7fffu + ((x >> 16) & 1u);            // RNE (inputs finite)
  return (unsigned short)(x >> 16);
}
__device__ __forceinline__ float bf2f(unsigned short u){
  unsigned x = ((unsigned)u) << 16;
  return __builtin_bit_cast(float, x);
}
__device__ __forceinline__ void glds16(const void* g, void* l){
  __builtin_amdgcn_global_load_lds(
      (const __attribute__((address_space(1))) void*)g,
      (__attribute__((address_space(3))) void*)l, 16, 0, 0);
}

// ---------------- merged cast kernel ----------------
__global__ __launch_bounds__(256) void k_cast(const float* __restrict__ G,
                                              const float* __restrict__ U0,
                                              const float* __restrict__ U1,
                                              const float* __restrict__ U2,
                                              unsigned short* __restrict__ Gbf,
                                              unsigned short* __restrict__ U0bf,
                                              unsigned short* __restrict__ U1T,
                                              unsigned short* __restrict__ U2T){
  const int blk = blockIdx.x;
  if (blk < 2112){
    const int i4 = blk * 256 + threadIdx.x;                // 0..540671
    const int NG4 = 2097152 / 4;
    const float4* src; unsigned short* dst; int j4;
    if (i4 < NG4){ src = (const float4*)G;  dst = Gbf;  j4 = i4; }
    else         { src = (const float4*)U0; dst = U0bf; j4 = i4 - NG4; }
    float4 v = src[j4];
    ushort4 o = make_ushort4(f2bf(v.x), f2bf(v.y), f2bf(v.z), f2bf(v.w));
    ((ushort4*)dst)[j4] = o;
  } else {
    const int b2 = blk - 2112;                             // 0..511
    const float* U = (b2 < 256) ? U1 : U2;
    unsigned short* UT = (b2 < 256) ? U1T : U2T;
    const int idx = (b2 & 255) * 256 + threadIdx.x;        // 0..65535
    const int d = idx >> 7, q = idx & 127;
    UT[q * 512 + d] = f2bf(U[idx]);
  }
}

// ---------------- UX GEMM (both modes, one dispatch) ----------------
__global__ __launch_bounds__(256) void k_ux2(const unsigned short* __restrict__ U1T,
                                             const unsigned short* __restrict__ U2T,
                                             const float* __restrict__ X1,
                                             const float* __restrict__ X2,
                                             float* __restrict__ OUTF,
                                             unsigned short* __restrict__ OUTT){
  const bool second = (blockIdx.y != 0);
  const unsigned short* UT = second ? U2T : U1T;
  const float* X = second ? X2 : X1;
  __shared__ __align__(16) unsigned char lds[16384 + 8192];
  unsigned char* ldsA = lds;
  unsigned char* ldsB = lds + 16384;
  const int tid = threadIdx.x, lane = tid & 63, wv = tid >> 6;
  const int wr = wv >> 1, wc = wv & 1;
  const int b0 = blockIdx.x * 64;
  f4 acc[4][2] = {};

  for (int it = 0; it < 8; ++it){
    const int k0 = it * 64;
#pragma unroll
    for (int i = 0; i < 4; ++i){
      const int L = (wv * 4 + i) * 1024 + lane * 16;
      const int row = L >> 7;
      const int ss = (lane & 7) ^ (row & 7);
      glds16(UT + (size_t)row * 512 + k0 + ss * 8, ldsA + (wv * 4 + i) * 1024);
    }
#pragma unroll
    for (int c = 0; c < 2; ++c){
      const int slot = c * 4 + wv;
      const int bRow = lane;
      bf8 v;
#pragma unroll
      for (int j = 0; j < 8; ++j)
        v[j] = (short)f2bf(X[(size_t)(k0 + slot * 8 + j) * 8192 + b0 + bRow]);
      *(bf8*)(ldsB + bRow * 128 + ((slot ^ (bRow & 7)) << 4)) = v;
    }
    __syncthreads();
#pragma unroll
    for (int kc = 0; kc < 2; ++kc){
      const int g = lane >> 4;
      bf8 a[4], b[2];
#pragma unroll
      for (int mf = 0; mf < 4; ++mf){
        const int r = wr * 64 + mf * 16 + (lane & 15);
        a[mf] = *(const bf8*)(ldsA + r * 128 + (((kc * 4 + g) ^ (r & 7)) << 4));
      }
#pragma unroll
      for (int nf = 0; nf < 2; ++nf){
        const int rb = wc * 32 + nf * 16 + (lane & 15);
        b[nf] = *(const bf8*)(ldsB + rb * 128 + (((kc * 4 + g) ^ (rb & 7)) << 4));
      }
#pragma unroll
      for (int mf = 0; mf < 4; ++mf)
#pragma unroll
        for (int nf = 0; nf < 2; ++nf)
          acc[mf][nf] = __builtin_amdgcn_mfma_f32_16x16x32_bf16(a[mf], b[nf], acc[mf][nf], 0, 0, 0);
    }
    __syncthreads();
  }

  if (!second){
#pragma unroll
    for (int mf = 0; mf < 4; ++mf)
#pragma unroll
      for (int nf = 0; nf < 2; ++nf)
#pragma unroll
        for (int j = 0; j < 4; ++j){
          const int q = wr * 64 + mf * 16 + (lane >> 4) * 4 + j;
          const int b = b0 + wc * 32 + nf * 16 + (lane & 15);
          OUTF[(size_t)q * 8192 + b] = acc[mf][nf][j];
        }
  } else {
#pragma unroll
    for (int mf = 0; mf < 4; ++mf)
#pragma unroll
      for (int nf = 0; nf < 2; ++nf){
        const int rBase = wr * 64 + mf * 16 + (lane >> 4) * 4;
        const int bL = wc * 32 + nf * 16 + (lane & 15);
        bf4 p;
#pragma unroll
        for (int j = 0; j < 4; ++j) p[j] = (short)f2bf(acc[mf][nf][j]);
        *(bf4*)(lds + ((bL * 256 + rBase * 2) ^ ((bL & 7) << 4))) = p;
      }
    __syncthreads();
#pragma unroll
    for (int u = 0; u < 4; ++u){
      const int sIdx = u * 256 + tid;
      const int bL = sIdx >> 4, slot = sIdx & 15;
      bf8 v = *(const bf8*)(lds + bL * 256 + ((slot ^ (bL & 7)) << 4));
      *(bf8*)(OUTT + (size_t)(b0 + bL) * 128 + slot * 8) = v;
    }
  }
}

// ---------------- core: wave-autonomous per-q GEMM, split-K(q)=8 ----------------
// Grid 512 blocks (2/CU). Block 128p x 128b, 4 waves, wave = 32p x 128b.
// Per-wave private ring: 2 x 8KB ([32p][128r] bf16, swizzled). 16 q per split.
__global__ __launch_bounds__(256, 2) void k_core(const unsigned short* __restrict__ Gbf,  // [128][16384]
                                                 const float* __restrict__ UX1,           // [128][8192]
                                                 const unsigned short* __restrict__ UX2T, // [8192][128]
                                                 unsigned short* __restrict__ PT){        // [8][8192][128] bf16
  __shared__ __align__(16) unsigned char lds[65536];       // 4 waves x 2 x 8KB
  const int tid = threadIdx.x, lane = tid & 63, wv = tid >> 6;
  const int g = lane >> 4, l15 = lane & 15;
  const int blk = blockIdx.x;                 // 0..511; round-robin => xcd = blk&7
  const int split = blk & 7;                  // one split per XCD
  const int b0 = (blk >> 3) * 128;            // 0..8064
  const int q0 = split * 16;
  const int p0 = wv * 32;
  unsigned char* ring = lds + wv * 16384;

  auto stageA = [&](int q, int buf){
    unsigned char* dst = ring + buf * 8192;
#pragma unroll
    for (int j = 0; j < 8; ++j){
      const int row = j * 4 + g;                           // 0..31
      const int ss = l15 ^ (row & 7);                      // source pre-swizzle
      glds16(Gbf + (size_t)(p0 + row) * 16384 + (size_t)q * 128 + ss * 8,
             dst + j * 1024);                              // HW adds lane*16
    }
  };

  // B hoist: [kc][nf] = 32 bf8 = 128 VGPR, for whole kernel
  bf8 Bf[4][8];
#pragma unroll
  for (int kc = 0; kc < 4; ++kc)
#pragma unroll
    for (int nf = 0; nf < 8; ++nf)
      Bf[kc][nf] = *(const bf8*)(UX2T + (size_t)(b0 + nf * 16 + l15) * 128 +
                                 kc * 32 + g * 8);
  stageA(q0 + 0, 0);
  stageA(q0 + 1, 1);

  f4 acc[2][8];
#pragma unroll
  for (int mf = 0; mf < 2; ++mf)
#pragma unroll
    for (int nf = 0; nf < 8; ++nf) acc[mf][nf] = (f4){0.f, 0.f, 0.f, 0.f};

  auto iter = [&](int i, bool stage_next){
    const unsigned char* A = ring + (i & 1) * 8192;
    // x1 loads first (so compiler's wait for them is vmcnt(stage glds), not 0)
    float xs[8];
#pragma unroll
    for (int nf = 0; nf < 8; ++nf)
      xs[nf] = UX1[(size_t)(q0 + i) * 8192 + b0 + nf * 16 + l15];
    bf8 a[2][4];
#pragma unroll
    for (int mf = 0; mf < 2; ++mf){
      const int row = mf * 16 + l15;
#pragma unroll
      for (int kc = 0; kc < 4; ++kc)
        a[mf][kc] = *(const bf8*)(A + row * 256 + ((((kc << 2) + g) ^ (row & 7)) << 4));
    }
    asm volatile("s_waitcnt lgkmcnt(0)" ::: "memory");     // reads done before re-stage
    __builtin_amdgcn_sched_barrier(0);
    if (stage_next) stageA(q0 + i + 2, i & 1);
#pragma unroll
    for (int mf = 0; mf < 2; ++mf)
#pragma unroll
      for (int nf = 0; nf < 8; ++nf){
        f4 y = __builtin_amdgcn_mfma_f32_16x16x32_bf16(a[mf][0], Bf[0][nf], (f4){0.f,0.f,0.f,0.f}, 0, 0, 0);
        y = __builtin_amdgcn_mfma_f32_16x16x32_bf16(a[mf][1], Bf[1][nf], y, 0, 0, 0);
        y = __builtin_amdgcn_mfma_f32_16x16x32_bf16(a[mf][2], Bf[2][nf], y, 0, 0, 0);
        y = __builtin_amdgcn_mfma_f32_16x16x32_bf16(a[mf][3], Bf[3][nf], y, 0, 0, 0);
        acc[mf][nf] += y * xs[nf];                         // fold x1 in f32
      }
  };

  // wave-autonomous main loop: per-wave counted vmcnt, NO barriers
  for (int i = 0; i < 14; ++i){
    asm volatile("s_waitcnt vmcnt(8)" ::: "memory");       // own stage(i) landed
    iter(i, true);
  }
  asm volatile("s_waitcnt vmcnt(8)" ::: "memory");
  iter(14, false);
  asm volatile("s_waitcnt vmcnt(0)" ::: "memory");
  iter(15, false);

  // epilogue: one barrier; bf16 convert -> swizzled LDS transpose -> PT[split][b][p]
  __syncthreads();
#pragma unroll
  for (int mf = 0; mf < 2; ++mf)
#pragma unroll
    for (int nf = 0; nf < 8; ++nf){
      const int bL = nf * 16 + l15;                        // 0..127
      const int pq = wv * 8 + mf * 4 + g;                  // p-quad 0..31
      bf4 o;
#pragma unroll
      for (int j = 0; j < 4; ++j) o[j] = (short)f2bf(acc[mf][nf][j]);
      *(bf4*)(lds + bL * 256 + ((pq ^ (bL & 7)) << 3)) = o;
    }
  __syncthreads();
#pragma unroll
  for (int rnd = 0; rnd < 8; ++rnd){
    const int idx = rnd * 256 + tid;                       // 2048 x 16B
    const int bL = idx >> 4, s8 = idx & 15;
    bf4 lo = *(const bf4*)(lds + bL * 256 + (((s8 * 2) ^ (bL & 7)) << 3));
    bf4 hi = *(const bf4*)(lds + bL * 256 + (((s8 * 2 + 1) ^ (bL & 7)) << 3));
    bf8 o;
#pragma unroll
    for (int j = 0; j < 4; ++j){ o[j] = lo[j]; o[4 + j] = hi[j]; }
    *(bf8*)(PT + (size_t)split * 1048576 + (size_t)(b0 + bL) * 128 + s8 * 8) = o;
  }
}

// ---------------- reduce 8 split partials -> coreT bf16 [8192][128] ----------------
__global__ __launch_bounds__(256) void k_red(const unsigned short* __restrict__ PT,
                                             unsigned short* __restrict__ coreT){
  const int c = blockIdx.x * 256 + threadIdx.x;            // 0..131071 bf8 chunks
  const bf8* P = (const bf8*)PT;
  float s[8] = {};
#pragma unroll
  for (int sp = 0; sp < 8; ++sp){
    bf8 v = P[c + sp * 131072];
#pragma unroll
    for (int j = 0; j < 8; ++j) s[j] += bf2f((unsigned short)v[j]);
  }
  bf8 o;
#pragma unroll
  for (int j = 0; j < 8; ++j) o[j] = (short)f2bf(s[j]);
  ((bf8*)coreT)[c] = o;
}

// ---------------- Z = U0 @ core: M=512, N=8192, K=128 ----------------
__global__ __launch_bounds__(256) void k_z(const unsigned short* __restrict__ U0bf,  // [512][128]
                                           const unsigned short* __restrict__ coreT, // [8192][128]
                                           float* __restrict__ Z){                   // [512][8192]
  __shared__ __align__(16) unsigned char lds[32768];
  unsigned char* ldsA = lds;
  unsigned char* ldsB = lds + 16384;
  const int tid = threadIdx.x, lane = tid & 63, wv = tid >> 6;
  const int wr = wv >> 1, wc = wv & 1;
  const int b0 = blockIdx.x * 128;
  const int d0 = blockIdx.y * 128;
  f4 acc[4][4] = {};

#pragma unroll
  for (int it = 0; it < 2; ++it){
    const int k0 = it * 64;
#pragma unroll
    for (int i = 0; i < 4; ++i){
      const int L = (wv * 4 + i) * 1024 + lane * 16;
      const int row = L >> 7;
      const int ss = (lane & 7) ^ (row & 7);
      glds16(U0bf + (size_t)(d0 + row) * 128 + k0 + ss * 8, ldsA + (wv * 4 + i) * 1024);
      glds16(coreT + (size_t)(b0 + row) * 128 + k0 + ss * 8, ldsB + (wv * 4 + i) * 1024);
    }
    __syncthreads();
#pragma unroll
    for (int kc = 0; kc < 2; ++kc){
      const int g = lane >> 4;
      bf8 a[4], b[4];
#pragma unroll
      for (int mf = 0; mf < 4; ++mf){
        const int r = wr * 64 + mf * 16 + (lane & 15);
        a[mf] = *(const bf8*)(ldsA + r * 128 + (((kc * 4 + g) ^ (r & 7)) << 4));
      }
#pragma unroll
      for (int nf = 0; nf < 4; ++nf){
        const int rb = wc * 64 + nf * 16 + (lane & 15);
        b[nf] = *(const bf8*)(ldsB + rb * 128 + (((kc * 4 + g) ^ (rb & 7)) << 4));
      }
#pragma unroll
      for (int mf = 0; mf < 4; ++mf)
#pragma unroll
        for (int nf = 0; nf < 4; ++nf)
          acc[mf][nf] = __builtin_amdgcn_mfma_f32_16x16x32_bf16(a[mf], b[nf], acc[mf][nf], 0, 0, 0);
    }
    __syncthreads();
  }
#pragma unroll
  for (int mf = 0; mf < 4; ++mf)
#pragma unroll
    for (int nf = 0; nf < 4; ++nf)
#pragma unroll
      for (int j = 0; j < 4; ++j){
        const int d = d0 + wr * 64 + mf * 16 + (lane >> 4) * 4 + j;
        const int b = b0 + wc * 64 + nf * 16 + (lane & 15);
        Z[(size_t)d * 8192 + b] = acc[mf][nf][j];
      }
}

// ---------------- host launch ----------------
extern "C" void kernel_launch(void* const* d_in, const int* in_sizes, int n_in,
                              void* d_out, int out_size, void* d_ws, size_t ws_size,
                              hipStream_t stream){
  const float* X1 = (const float*)d_in[0];
  const float* X2 = (const float*)d_in[1];
  const float* U0 = (const float*)d_in[2];
  const float* U1 = (const float*)d_in[3];
  const float* U2 = (const float*)d_in[4];
  const float* G  = (const float*)d_in[5];
  float* Z = (float*)d_out;

  char* ws = (char*)d_ws;
  unsigned short* Gbf   = (unsigned short*)(ws);              //  4,194,304 B
  unsigned short* U0bf  = (unsigned short*)(ws + 4194304);    //    131,072 B
  unsigned short* U1T   = (unsigned short*)(ws + 4325376);    //    131,072 B
  unsigned short* U2T   = (unsigned short*)(ws + 4456448);    //    131,072 B
  float*          UX1   = (float*)         (ws + 4587520);    //  4,194,304 B
  unsigned short* UX2T  = (unsigned short*)(ws + 8781824);    //  2,097,152 B
  unsigned short* coreT = (unsigned short*)(ws + 10878976);   //  2,097,152 B
  unsigned short* PT    = (unsigned short*)(ws + 12976128);   // 16,777,216 B (bf16 x8 splits)

  k_cast<<<dim3(2624), dim3(256), 0, stream>>>(G, U0, U1, U2, Gbf, U0bf, U1T, U2T);
  k_ux2 <<<dim3(128, 2), dim3(256), 0, stream>>>(U1T, U2T, X1, X2, UX1, UX2T);
  k_core<<<dim3(512), dim3(256), 0, stream>>>(Gbf, UX1, UX2T, PT);
  k_red <<<dim3(512), dim3(256), 0, stream>>>(PT, coreT);
  k_z   <<<dim3(64, 4), dim3(256), 0, stream>>>(U0bf, coreT, Z);
}

// Round 7
// 71.112 us; speedup vs baseline: 1.0323x; 1.0323x over previous
//
#include <hip/hip_runtime.h>
#include <hip/hip_bf16.h>
#include <stdint.h>

// FullTucker: Z = U0 @ einsum('pqr,qb,rb->pb', G, U1^T@X1, U2^T@X2)
// D_OUT=D1=D2=512, R0=R1=R2=128, BATCH=8192. f32 in/out; bf16 MFMA inside.
// k_core: core[p,b] = sum_q x1[q,b] * (sum_r G[p,q,r]*u2[r,b])
//   m201-style 2-phase-per-q barrier-paced schedule: per phase
//   {ds_read A-frags || stage glds -> barrier -> lgkmcnt(0) -> setprio MFMA
//    cluster -> f32 x1-fold fmacs -> barrier}, A ring depth-3 with counted
//   vmcnt(4) once per q (never drain-0 in loop). B (UX2T) hoisted 64 VGPR
//   for the whole kernel (zero B LDS reads); x1 staged once in LDS.

typedef __attribute__((ext_vector_type(8))) short bf8;   // 8 bf16 (4 VGPR)
typedef __attribute__((ext_vector_type(4))) short bf4;   // 4 bf16 (8B)
typedef __attribute__((ext_vector_type(4))) float f4;    // 4 f32

__device__ __forceinline__ unsigned short f2bf(float f){
  unsigned x = __builtin_bit_cast(unsigned, f);
  x += 0x7fffu + ((x >> 16) & 1u);            // RNE (inputs finite)
  return (unsigned short)(x >> 16);
}
__device__ __forceinline__ float bf2f(unsigned short u){
  unsigned x = ((unsigned)u) << 16;
  return __builtin_bit_cast(float, x);
}
__device__ __forceinline__ void glds16(const void* g, void* l){
  __builtin_amdgcn_global_load_lds(
      (const __attribute__((address_space(1))) void*)g,
      (__attribute__((address_space(3))) void*)l, 16, 0, 0);
}

// ---------------- merged cast kernel ----------------
__global__ __launch_bounds__(256) void k_cast(const float* __restrict__ G,
                                              const float* __restrict__ U0,
                                              const float* __restrict__ U1,
                                              const float* __restrict__ U2,
                                              unsigned short* __restrict__ Gbf,
                                              unsigned short* __restrict__ U0bf,
                                              unsigned short* __restrict__ U1T,
                                              unsigned short* __restrict__ U2T){
  const int blk = blockIdx.x;
  if (blk < 2112){
    const int i4 = blk * 256 + threadIdx.x;                // 0..540671
    const int NG4 = 2097152 / 4;
    const float4* src; unsigned short* dst; int j4;
    if (i4 < NG4){ src = (const float4*)G;  dst = Gbf;  j4 = i4; }
    else         { src = (const float4*)U0; dst = U0bf; j4 = i4 - NG4; }
    float4 v = src[j4];
    ushort4 o = make_ushort4(f2bf(v.x), f2bf(v.y), f2bf(v.z), f2bf(v.w));
    ((ushort4*)dst)[j4] = o;
  } else {
    const int b2 = blk - 2112;                             // 0..511
    const float* U = (b2 < 256) ? U1 : U2;
    unsigned short* UT = (b2 < 256) ? U1T : U2T;
    const int idx = (b2 & 255) * 256 + threadIdx.x;        // 0..65535
    const int d = idx >> 7, q = idx & 127;
    UT[q * 512 + d] = f2bf(U[idx]);
  }
}

// ---------------- UX GEMM (both modes, one dispatch) ----------------
__global__ __launch_bounds__(256) void k_ux2(const unsigned short* __restrict__ U1T,
                                             const unsigned short* __restrict__ U2T,
                                             const float* __restrict__ X1,
                                             const float* __restrict__ X2,
                                             float* __restrict__ OUTF,
                                             unsigned short* __restrict__ OUTT){
  const bool second = (blockIdx.y != 0);
  const unsigned short* UT = second ? U2T : U1T;
  const float* X = second ? X2 : X1;
  __shared__ __align__(16) unsigned char lds[16384 + 8192];
  unsigned char* ldsA = lds;
  unsigned char* ldsB = lds + 16384;
  const int tid = threadIdx.x, lane = tid & 63, wv = tid >> 6;
  const int wr = wv >> 1, wc = wv & 1;
  const int b0 = blockIdx.x * 64;
  f4 acc[4][2] = {};

  for (int it = 0; it < 8; ++it){
    const int k0 = it * 64;
#pragma unroll
    for (int i = 0; i < 4; ++i){
      const int L = (wv * 4 + i) * 1024 + lane * 16;
      const int row = L >> 7;
      const int ss = (lane & 7) ^ (row & 7);
      glds16(UT + (size_t)row * 512 + k0 + ss * 8, ldsA + (wv * 4 + i) * 1024);
    }
#pragma unroll
    for (int c = 0; c < 2; ++c){
      const int slot = c * 4 + wv;
      const int bRow = lane;
      bf8 v;
#pragma unroll
      for (int j = 0; j < 8; ++j)
        v[j] = (short)f2bf(X[(size_t)(k0 + slot * 8 + j) * 8192 + b0 + bRow]);
      *(bf8*)(ldsB + bRow * 128 + ((slot ^ (bRow & 7)) << 4)) = v;
    }
    __syncthreads();
#pragma unroll
    for (int kc = 0; kc < 2; ++kc){
      const int g = lane >> 4;
      bf8 a[4], b[2];
#pragma unroll
      for (int mf = 0; mf < 4; ++mf){
        const int r = wr * 64 + mf * 16 + (lane & 15);
        a[mf] = *(const bf8*)(ldsA + r * 128 + (((kc * 4 + g) ^ (r & 7)) << 4));
      }
#pragma unroll
      for (int nf = 0; nf < 2; ++nf){
        const int rb = wc * 32 + nf * 16 + (lane & 15);
        b[nf] = *(const bf8*)(ldsB + rb * 128 + (((kc * 4 + g) ^ (rb & 7)) << 4));
      }
#pragma unroll
      for (int mf = 0; mf < 4; ++mf)
#pragma unroll
        for (int nf = 0; nf < 2; ++nf)
          acc[mf][nf] = __builtin_amdgcn_mfma_f32_16x16x32_bf16(a[mf], b[nf], acc[mf][nf], 0, 0, 0);
    }
    __syncthreads();
  }

  if (!second){
#pragma unroll
    for (int mf = 0; mf < 4; ++mf)
#pragma unroll
      for (int nf = 0; nf < 2; ++nf)
#pragma unroll
        for (int j = 0; j < 4; ++j){
          const int q = wr * 64 + mf * 16 + (lane >> 4) * 4 + j;
          const int b = b0 + wc * 32 + nf * 16 + (lane & 15);
          OUTF[(size_t)q * 8192 + b] = acc[mf][nf][j];
        }
  } else {
#pragma unroll
    for (int mf = 0; mf < 4; ++mf)
#pragma unroll
      for (int nf = 0; nf < 2; ++nf){
        const int rBase = wr * 64 + mf * 16 + (lane >> 4) * 4;
        const int bL = wc * 32 + nf * 16 + (lane & 15);
        bf4 p;
#pragma unroll
        for (int j = 0; j < 4; ++j) p[j] = (short)f2bf(acc[mf][nf][j]);
        *(bf4*)(lds + ((bL * 256 + rBase * 2) ^ ((bL & 7) << 4))) = p;
      }
    __syncthreads();
#pragma unroll
    for (int u = 0; u < 4; ++u){
      const int sIdx = u * 256 + tid;
      const int bL = sIdx >> 4, slot = sIdx & 15;
      bf8 v = *(const bf8*)(lds + bL * 256 + ((slot ^ (bL & 7)) << 4));
      *(bf8*)(OUTT + (size_t)(b0 + bL) * 128 + slot * 8) = v;
    }
  }
}

// ---------------- core: 8-phase-style barrier-paced GEMM, split-K(q)=8 ----------------
// Grid 256 (1 block/CU). Block 128p x 256b, 8 waves (2x4), wave 64p x 64b.
// LDS: A ring 3 x 32KB ([128p][128r] bf16, swizzled) + x1 [16q][256b] f32 16KB.
__global__ __launch_bounds__(512, 2) void k_core(const unsigned short* __restrict__ Gbf,  // [128][16384]
                                                 const float* __restrict__ UX1,           // [128][8192]
                                                 const unsigned short* __restrict__ UX2T, // [8192][128]
                                                 unsigned short* __restrict__ PT){        // [8][8192][128] bf16
  __shared__ __align__(16) unsigned char lds[114688];      // 3x32K ring + 16K x1
  unsigned char* ldsX = lds + 98304;
  const int tid = threadIdx.x, lane = tid & 63, wv = tid >> 6;
  const int g = lane >> 4, l15 = lane & 15;
  const int wr = wv >> 2, wc = wv & 3;          // 2 x 4 waves; wave 64p x 64b
  const int blk = blockIdx.x;                   // 0..255; round-robin => xcd = blk&7
  const int split = blk & 7;                    // one split per XCD
  const int b0 = (blk >> 3) * 256;              // 0..7936
  const int q0 = split * 16;

  auto stageA = [&](int q, int buf, int rnd){   // one 8KB round of the 32KB q-slice
    const int off = rnd * 8192 + wv * 1024 + lane * 16;
    const int row = off >> 8;                   // p-row 0..127
    const int ss = ((off >> 4) & 15) ^ (row & 7);
    glds16(Gbf + (size_t)row * 16384 + (size_t)q * 128 + ss * 8,
           lds + buf * 32768 + off);
  };

  // B hoist FIRST (16 bf8 = 64 VGPR; compiler's wait leaves later glds in flight)
  bf8 Bf[4][4];
#pragma unroll
  for (int kc = 0; kc < 4; ++kc)
#pragma unroll
    for (int nf = 0; nf < 4; ++nf)
      Bf[kc][nf] = *(const bf8*)(UX2T + (size_t)(b0 + wc * 64 + nf * 16 + l15) * 128 +
                                 kc * 32 + g * 8);
  // x1 slice [16q][256b] f32 -> LDS (2 glds)
#pragma unroll
  for (int rnd = 0; rnd < 2; ++rnd){
    const int off = rnd * 8192 + wv * 1024 + lane * 16;
    const int row = off >> 10;                  // q-row 0..15
    glds16(UX1 + (size_t)(q0 + row) * 8192 + b0 + ((off >> 2) & 255), ldsX + off);
  }
  // prologue stages: q0 -> buf0, q0+1 -> buf1
#pragma unroll
  for (int rnd = 0; rnd < 4; ++rnd) stageA(q0, 0, rnd);
#pragma unroll
  for (int rnd = 0; rnd < 4; ++rnd) stageA(q0 + 1, 1, rnd);

  f4 acc[4][4];
#pragma unroll
  for (int mf = 0; mf < 4; ++mf)
#pragma unroll
    for (int nf = 0; nf < 4; ++nf) acc[mf][nf] = (f4){0.f, 0.f, 0.f, 0.f};
  float xs[4];

  // ensure x1 + stage(q0) landed (stage(q0+1)'s 4 glds may remain in flight)
  asm volatile("s_waitcnt vmcnt(4)" ::: "memory");
  __builtin_amdgcn_s_barrier();

  // one phase: mf-pair ph*2..ph*2+1, all 4 kc. vm: -1 none, 4 counted, 0 drain.
  auto phase = [&](int i, const unsigned char* A, int ph, bool doStage,
                   int stq, int sbuf, int vm){
    bf8 a[2][4];
#pragma unroll
    for (int mfp = 0; mfp < 2; ++mfp){
      const int row = wr * 64 + (ph * 2 + mfp) * 16 + l15;
#pragma unroll
      for (int kc = 0; kc < 4; ++kc)
        a[mfp][kc] = *(const bf8*)(A + row * 256 + ((((kc << 2) + g) ^ (row & 7)) << 4));
    }
    if (ph == 0){
#pragma unroll
      for (int nf = 0; nf < 4; ++nf)
        xs[nf] = *(const float*)(ldsX + i * 1024 + (wc * 64 + nf * 16 + l15) * 4);
    }
    if (doStage){ stageA(stq, sbuf, ph * 2); stageA(stq, sbuf, ph * 2 + 1); }
    __builtin_amdgcn_s_barrier();
    asm volatile("s_waitcnt lgkmcnt(0)" ::: "memory");
    __builtin_amdgcn_sched_barrier(0);
    __builtin_amdgcn_s_setprio(1);
    f4 y[2][4];
#pragma unroll
    for (int mfp = 0; mfp < 2; ++mfp)
#pragma unroll
      for (int nf = 0; nf < 4; ++nf){
        f4 t = __builtin_amdgcn_mfma_f32_16x16x32_bf16(a[mfp][0], Bf[0][nf], (f4){0.f,0.f,0.f,0.f}, 0, 0, 0);
        t = __builtin_amdgcn_mfma_f32_16x16x32_bf16(a[mfp][1], Bf[1][nf], t, 0, 0, 0);
        t = __builtin_amdgcn_mfma_f32_16x16x32_bf16(a[mfp][2], Bf[2][nf], t, 0, 0, 0);
        y[mfp][nf] = __builtin_amdgcn_mfma_f32_16x16x32_bf16(a[mfp][3], Bf[3][nf], t, 0, 0, 0);
      }
    __builtin_amdgcn_s_setprio(0);
#pragma unroll
    for (int mfp = 0; mfp < 2; ++mfp)
#pragma unroll
      for (int nf = 0; nf < 4; ++nf)
        acc[ph * 2 + mfp][nf] += y[mfp][nf] * xs[nf];     // fold x1 in f32
    if (vm == 4)      asm volatile("s_waitcnt vmcnt(4)" ::: "memory");
    else if (vm == 0) asm volatile("s_waitcnt vmcnt(0)" ::: "memory");
    __builtin_amdgcn_s_barrier();
  };

  int cur = 0;
  for (int i = 0; i < 14; ++i){
    const unsigned char* A = lds + cur * 32768;
    int sbuf = cur + 2; if (sbuf >= 3) sbuf -= 3;
    phase(i, A, 0, true, q0 + i + 2, sbuf, -1);
    phase(i, A, 1, true, q0 + i + 2, sbuf, 4);   // counted: stage(i+1) landed
    ++cur; if (cur == 3) cur = 0;
  }
  {
    const unsigned char* A = lds + cur * 32768;
    phase(14, A, 0, false, 0, 0, -1);
    phase(14, A, 1, false, 0, 0, 0);             // drain: stage(15) landed
    ++cur; if (cur == 3) cur = 0;
  }
  {
    const unsigned char* A = lds + cur * 32768;
    phase(15, A, 0, false, 0, 0, -1);
    phase(15, A, 1, false, 0, 0, -1);
  }

  // epilogue: acc -> PT[split][b][p] bf16 via swizzled LDS transpose (64KB in ring)
  __syncthreads();
#pragma unroll
  for (int mf = 0; mf < 4; ++mf)
#pragma unroll
    for (int nf = 0; nf < 4; ++nf){
      const int bL = wc * 64 + nf * 16 + l15;    // 0..255
      const int pq = wr * 16 + mf * 4 + g;       // p-quad 0..31
      bf4 o;
#pragma unroll
      for (int j = 0; j < 4; ++j) o[j] = (short)f2bf(acc[mf][nf][j]);
      *(bf4*)(lds + bL * 256 + ((pq ^ (bL & 7)) << 3)) = o;
    }
  __syncthreads();
#pragma unroll
  for (int rnd = 0; rnd < 8; ++rnd){
    const int idx = rnd * 512 + tid;             // 4096 x 16B chunks
    const int bL = idx >> 4, s8 = idx & 15;
    bf4 lo = *(const bf4*)(lds + bL * 256 + (((s8 * 2) ^ (bL & 7)) << 3));
    bf4 hi = *(const bf4*)(lds + bL * 256 + (((s8 * 2 + 1) ^ (bL & 7)) << 3));
    bf8 o;
#pragma unroll
    for (int j = 0; j < 4; ++j){ o[j] = lo[j]; o[4 + j] = hi[j]; }
    *(bf8*)(PT + (size_t)split * 1048576 + (size_t)(b0 + bL) * 128 + s8 * 8) = o;
  }
}

// ---------------- reduce 8 split partials -> coreT bf16 [8192][128] ----------------
__global__ __launch_bounds__(256) void k_red(const unsigned short* __restrict__ PT,
                                             unsigned short* __restrict__ coreT){
  const int c = blockIdx.x * 256 + threadIdx.x;            // 0..131071 bf8 chunks
  const bf8* P = (const bf8*)PT;
  float s[8] = {};
#pragma unroll
  for (int sp = 0; sp < 8; ++sp){
    bf8 v = P[c + sp * 131072];
#pragma unroll
    for (int j = 0; j < 8; ++j) s[j] += bf2f((unsigned short)v[j]);
  }
  bf8 o;
#pragma unroll
  for (int j = 0; j < 8; ++j) o[j] = (short)f2bf(s[j]);
  ((bf8*)coreT)[c] = o;
}

// ---------------- Z = U0 @ core: M=512, N=8192, K=128 ----------------
__global__ __launch_bounds__(256) void k_z(const unsigned short* __restrict__ U0bf,  // [512][128]
                                           const unsigned short* __restrict__ coreT, // [8192][128]
                                           float* __restrict__ Z){                   // [512][8192]
  __shared__ __align__(16) unsigned char lds[32768];
  unsigned char* ldsA = lds;
  unsigned char* ldsB = lds + 16384;
  const int tid = threadIdx.x, lane = tid & 63, wv = tid >> 6;
  const int wr = wv >> 1, wc = wv & 1;
  const int b0 = blockIdx.x * 128;
  const int d0 = blockIdx.y * 128;
  f4 acc[4][4] = {};

#pragma unroll
  for (int it = 0; it < 2; ++it){
    const int k0 = it * 64;
#pragma unroll
    for (int i = 0; i < 4; ++i){
      const int L = (wv * 4 + i) * 1024 + lane * 16;
      const int row = L >> 7;
      const int ss = (lane & 7) ^ (row & 7);
      glds16(U0bf + (size_t)(d0 + row) * 128 + k0 + ss * 8, ldsA + (wv * 4 + i) * 1024);
      glds16(coreT + (size_t)(b0 + row) * 128 + k0 + ss * 8, ldsB + (wv * 4 + i) * 1024);
    }
    __syncthreads();
#pragma unroll
    for (int kc = 0; kc < 2; ++kc){
      const int g = lane >> 4;
      bf8 a[4], b[4];
#pragma unroll
      for (int mf = 0; mf < 4; ++mf){
        const int r = wr * 64 + mf * 16 + (lane & 15);
        a[mf] = *(const bf8*)(ldsA + r * 128 + (((kc * 4 + g) ^ (r & 7)) << 4));
      }
#pragma unroll
      for (int nf = 0; nf < 4; ++nf){
        const int rb = wc * 64 + nf * 16 + (lane & 15);
        b[nf] = *(const bf8*)(ldsB + rb * 128 + (((kc * 4 + g) ^ (rb & 7)) << 4));
      }
#pragma unroll
      for (int mf = 0; mf < 4; ++mf)
#pragma unroll
        for (int nf = 0; nf < 4; ++nf)
          acc[mf][nf] = __builtin_amdgcn_mfma_f32_16x16x32_bf16(a[mf], b[nf], acc[mf][nf], 0, 0, 0);
    }
    __syncthreads();
  }
#pragma unroll
  for (int mf = 0; mf < 4; ++mf)
#pragma unroll
    for (int nf = 0; nf < 4; ++nf)
#pragma unroll
      for (int j = 0; j < 4; ++j){
        const int d = d0 + wr * 64 + mf * 16 + (lane >> 4) * 4 + j;
        const int b = b0 + wc * 64 + nf * 16 + (lane & 15);
        Z[(size_t)d * 8192 + b] = acc[mf][nf][j];
      }
}

// ---------------- host launch ----------------
extern "C" void kernel_launch(void* const* d_in, const int* in_sizes, int n_in,
                              void* d_out, int out_size, void* d_ws, size_t ws_size,
                              hipStream_t stream){
  const float* X1 = (const float*)d_in[0];
  const float* X2 = (const float*)d_in[1];
  const float* U0 = (const float*)d_in[2];
  const float* U1 = (const float*)d_in[3];
  const float* U2 = (const float*)d_in[4];
  const float* G  = (const float*)d_in[5];
  float* Z = (float*)d_out;

  char* ws = (char*)d_ws;
  unsigned short* Gbf   = (unsigned short*)(ws);              //  4,194,304 B
  unsigned short* U0bf  = (unsigned short*)(ws + 4194304);    //    131,072 B
  unsigned short* U1T   = (unsigned short*)(ws + 4325376);    //    131,072 B
  unsigned short* U2T   = (unsigned short*)(ws + 4456448);    //    131,072 B
  float*          UX1   = (float*)         (ws + 4587520);    //  4,194,304 B
  unsigned short* UX2T  = (unsigned short*)(ws + 8781824);    //  2,097,152 B
  unsigned short* coreT = (unsigned short*)(ws + 10878976);   //  2,097,152 B
  unsigned short* PT    = (unsigned short*)(ws + 12976128);   // 16,777,216 B (bf16 x8 splits)

  k_cast<<<dim3(2624), dim3(256), 0, stream>>>(G, U0, U1, U2, Gbf, U0bf, U1T, U2T);
  k_ux2 <<<dim3(128, 2), dim3(256), 0, stream>>>(U1T, U2T, X1, X2, UX1, UX2T);
  k_core<<<dim3(256), dim3(512), 0, stream>>>(Gbf, UX1, UX2T, PT);
  k_red <<<dim3(512), dim3(256), 0, stream>>>(PT, coreT);
  k_z   <<<dim3(64, 4), dim3(256), 0, stream>>>(U0bf, coreT, Z);
}